// Round 2
// baseline (1166.623 us; speedup 1.0000x reference)
//
#include <hip/hip_runtime.h>
#include <hip/hip_bf16.h>
#include <math.h>

#define BDIM 2
#define SDIM 2048
#define HDIM 16
#define HD 128
#define HID 2048
#define FFD 8192
#define NTOK (BDIM*SDIM)
#define QKVW (3*HID)

typedef __hip_bfloat16 bf16;
typedef __attribute__((ext_vector_type(8))) short short8;
typedef __attribute__((ext_vector_type(4))) short short4_;
typedef __attribute__((ext_vector_type(4))) float floatx4;

__device__ inline short bfbits(float f) {
  bf16 h = __float2bfloat16(f);
  short s;
  __builtin_memcpy(&s, &h, 2);
  return s;
}

// ---------------- weight transpose + f32->bf16 convert ----------------
// W: K x N (row-major f32)  ->  Wt: N x K (row-major bf16)
__global__ __launch_bounds__(256) void transpose_cvt(
    const float* __restrict__ W, bf16* __restrict__ Wt, int K, int N)
{
  __shared__ float tile[32][33];
  int n0 = blockIdx.x * 32, k0 = blockIdx.y * 32;
  int tx = threadIdx.x, ty = threadIdx.y;  // 32 x 8
  #pragma unroll
  for (int r = ty; r < 32; r += 8)
    tile[r][tx] = W[(size_t)(k0 + r) * N + n0 + tx];
  __syncthreads();
  #pragma unroll
  for (int r = ty; r < 32; r += 8)
    Wt[(size_t)(n0 + r) * K + k0 + tx] = __float2bfloat16(tile[tx][r]);
}

// ---------------- fused LayerNorm (both LN1 and LN2) ----------------
__global__ __launch_bounds__(256) void ln_both(
    const float* __restrict__ x,
    const float* __restrict__ g1, const float* __restrict__ b1,
    const float* __restrict__ g2, const float* __restrict__ b2,
    bf16* __restrict__ o1, bf16* __restrict__ o2)
{
  int row = blockIdx.x;
  int tid = threadIdx.x;
  const float4* xr = (const float4*)(x + (size_t)row * HID);
  float4 va = xr[tid], vb = xr[tid + 256];
  float s = va.x + va.y + va.z + va.w + vb.x + vb.y + vb.z + vb.w;
  float q = va.x*va.x + va.y*va.y + va.z*va.z + va.w*va.w
          + vb.x*vb.x + vb.y*vb.y + vb.z*vb.z + vb.w*vb.w;
  #pragma unroll
  for (int off = 1; off < 64; off <<= 1) {
    s += __shfl_xor(s, off);
    q += __shfl_xor(q, off);
  }
  __shared__ float red[8];
  int wave = tid >> 6;
  if ((tid & 63) == 0) { red[wave] = s; red[4 + wave] = q; }
  __syncthreads();
  s = red[0] + red[1] + red[2] + red[3];
  q = red[4] + red[5] + red[6] + red[7];
  float mu = s * (1.0f / HID);
  float var = q * (1.0f / HID) - mu * mu;
  float rs = rsqrtf(var + 1e-5f);

  const float4* g1v = (const float4*)g1; const float4* b1v = (const float4*)b1;
  const float4* g2v = (const float4*)g2; const float4* b2v = (const float4*)b2;
  short4_* o1v = (short4_*)(o1 + (size_t)row * HID);
  short4_* o2v = (short4_*)(o2 + (size_t)row * HID);
  #pragma unroll
  for (int p = 0; p < 2; ++p) {
    int e = tid + p * 256;
    float4 xv = (p == 0) ? va : vb;
    float4 gv = g1v[e], bv = b1v[e];
    short4_ pk;
    pk[0] = bfbits((xv.x - mu) * rs * gv.x + bv.x);
    pk[1] = bfbits((xv.y - mu) * rs * gv.y + bv.y);
    pk[2] = bfbits((xv.z - mu) * rs * gv.z + bv.z);
    pk[3] = bfbits((xv.w - mu) * rs * gv.w + bv.w);
    o1v[e] = pk;
    gv = g2v[e]; bv = b2v[e];
    pk[0] = bfbits((xv.x - mu) * rs * gv.x + bv.x);
    pk[1] = bfbits((xv.y - mu) * rs * gv.y + bv.y);
    pk[2] = bfbits((xv.z - mu) * rs * gv.z + bv.z);
    pk[3] = bfbits((xv.w - mu) * rs * gv.w + bv.w);
    o2v[e] = pk;
  }
}

// ---------------- bf16 GEMM, B^T layout (m97 structure) ----------------
// A: M x K bf16 row-major. Bt: N x K bf16 row-major. 128x128 tile, BK=32.
// EPI 1: bf16 out = gelu(acc + bias)
// EPI 2: f32 out = acc + bias + (f32)r1b + r2
// EPI 3: bf16 out = acc + bias
template<int EPI>
__global__ __launch_bounds__(256) void gemm_bt(
    const bf16* __restrict__ A, const bf16* __restrict__ Bt,
    const float* __restrict__ bias,
    float* __restrict__ Cf, bf16* __restrict__ Cb,
    const bf16* __restrict__ r1b, const float* __restrict__ r2,
    int M, int N, int K)
{
  __shared__ bf16 As[128 * 32];
  __shared__ bf16 Bs[128 * 32];
  const int tid = threadIdx.x;
  const int wave = tid >> 6, lane = tid & 63;
  const int quad = lane >> 4, l16 = lane & 15;
  const int n0 = blockIdx.x * 128, m0 = blockIdx.y * 128;
  const int wm = (wave >> 1) * 64, wn = (wave & 1) * 64;
  const int lrow = lane >> 2, lcol = (lane & 3) * 8;

  floatx4 acc[4][4];
  #pragma unroll
  for (int i = 0; i < 4; ++i)
    #pragma unroll
    for (int j = 0; j < 4; ++j) acc[i][j] = (floatx4)0.0f;

  const int KT = K >> 5;
  for (int kt = 0; kt < KT; ++kt) {
    #pragma unroll
    for (int t = 0; t < 2; ++t) {
      int c = wave * 2 + t;
      const bf16* ga = A + (size_t)(m0 + c * 16 + lrow) * K + kt * 32 + lcol;
      const bf16* gb = Bt + (size_t)(n0 + c * 16 + lrow) * K + kt * 32 + lcol;
      __builtin_amdgcn_global_load_lds(
          (const __attribute__((address_space(1))) void*)ga,
          (__attribute__((address_space(3))) void*)&As[c * 512], 16, 0, 0);
      __builtin_amdgcn_global_load_lds(
          (const __attribute__((address_space(1))) void*)gb,
          (__attribute__((address_space(3))) void*)&Bs[c * 512], 16, 0, 0);
    }
    __syncthreads();
    short8 av[4], bv[4];
    #pragma unroll
    for (int i = 0; i < 4; ++i)
      av[i] = *(const short8*)&As[(wm + i * 16 + l16) * 32 + quad * 8];
    #pragma unroll
    for (int j = 0; j < 4; ++j)
      bv[j] = *(const short8*)&Bs[(wn + j * 16 + l16) * 32 + quad * 8];
    #pragma unroll
    for (int i = 0; i < 4; ++i)
      #pragma unroll
      for (int j = 0; j < 4; ++j)
        acc[i][j] = __builtin_amdgcn_mfma_f32_16x16x32_bf16(av[i], bv[j], acc[i][j], 0, 0, 0);
    __syncthreads();
  }

  #pragma unroll
  for (int i = 0; i < 4; ++i) {
    #pragma unroll
    for (int j = 0; j < 4; ++j) {
      int col = n0 + wn + j * 16 + l16;
      float bsv = bias[col];
      #pragma unroll
      for (int r = 0; r < 4; ++r) {
        int row = m0 + wm + i * 16 + quad * 4 + r;
        size_t idx = (size_t)row * N + col;
        float v = acc[i][j][r] + bsv;
        if (EPI == 1) {
          v = 0.5f * v * (1.0f + erff(v * 0.70710678118654752f));
          Cb[idx] = __float2bfloat16(v);
        } else if (EPI == 2) {
          Cf[idx] = v + __bfloat162float(r1b[idx]) + r2[idx];
        } else {
          Cb[idx] = __float2bfloat16(v);
        }
      }
    }
  }
}

// ---------------- RoPE in-place on bf16 qkv + V transpose ----------------
// qkv: [NTOK][6144] bf16, per head h: [h*384+0:128]=q, [+128]=k, [+256]=v.
// RoPE modifies only dims [0,32) of q and k, in-place (pair d / d+16 handled
// by one thread -> no cross-thread RAW hazard). v copied to vT[bh][128][S].
__global__ __launch_bounds__(256) void rope_vt(
    bf16* __restrict__ qkv, bf16* __restrict__ vT)
{
  int bh = blockIdx.x, s0 = blockIdx.y * 32;
  int b = bh >> 4, h = bh & 15;
  int tid = threadIdx.x;
  __shared__ bf16 vs[32][136];

  // rope: 32 tokens x 16 pairs = 512 items
  for (int idx = tid; idx < 512; idx += 256) {
    int sl = idx >> 4, d = idx & 15;
    int s = s0 + sl;
    bf16* base = qkv + (size_t)(b * SDIM + s) * QKVW + h * 384;
    float fr = (float)s * expf(-(float)d * 0.5756462732485114f); // ln(10000)/16
    float c = cosf(fr), sn = sinf(fr);
    float q1 = __bfloat162float(base[d]);
    float q2 = __bfloat162float(base[d + 16]);
    float k1 = __bfloat162float(base[128 + d]);
    float k2 = __bfloat162float(base[128 + d + 16]);
    base[d]        = __float2bfloat16(q1 * c - q2 * sn);
    base[d + 16]   = __float2bfloat16(q2 * c + q1 * sn);
    base[128 + d]      = __float2bfloat16(k1 * c - k2 * sn);
    base[128 + d + 16] = __float2bfloat16(k2 * c + k1 * sn);
  }

  // V transpose via LDS
  for (int idx = tid; idx < 32 * 128; idx += 256) {
    int sl = idx >> 7, d = idx & 127;
    vs[sl][d] = qkv[(size_t)(b * SDIM + s0 + sl) * QKVW + h * 384 + 256 + d];
  }
  __syncthreads();
  for (int idx = tid; idx < 32 * 128; idx += 256) {
    int d = idx >> 5, sl = idx & 31;
    vT[((size_t)bh * HD + d) * SDIM + s0 + sl] = vs[sl][d];
  }
}

// ---------------- flash attention, one wave per 16 q-rows ----------------
__global__ __launch_bounds__(64) void flash_attn(
    const bf16* __restrict__ qkv, const bf16* __restrict__ vT,
    bf16* __restrict__ ctx)
{
  int bh = blockIdx.x, qt = blockIdx.y;
  int b = bh >> 4, h = bh & 15;
  int lane = threadIdx.x, quad = lane >> 4, l16 = lane & 15;
  int q0 = qt * 16;
  const bf16* Qb = qkv + (size_t)b * SDIM * QKVW + h * 384;        // +row*6144
  const bf16* Kb = Qb + 128;
  const bf16* Vb = vT + (size_t)bh * HD * SDIM;
  __shared__ bf16 Ps[16][32];

  short8 aq[4];
  #pragma unroll
  for (int c = 0; c < 4; ++c)
    aq[c] = *(const short8*)&Qb[(size_t)(q0 + l16) * QKVW + c * 32 + quad * 8];

  floatx4 o[8];
  #pragma unroll
  for (int d = 0; d < 8; ++d) o[d] = (floatx4)0.0f;
  float m_run[4] = {-INFINITY, -INFINITY, -INFINITY, -INFINITY};
  float l_run[4] = {0.0f, 0.0f, 0.0f, 0.0f};
  const float scale = 0.08838834764831845f;  // 1/sqrt(128)

  int tmax = (q0 + 15) >> 5;
  for (int t = 0; t <= tmax; ++t) {
    int k0 = t * 32;
    floatx4 sc[2];
    sc[0] = (floatx4)0.0f; sc[1] = (floatx4)0.0f;
    #pragma unroll
    for (int nh = 0; nh < 2; ++nh) {
      const bf16* kp = &Kb[(size_t)(k0 + nh * 16 + l16) * QKVW + quad * 8];
      #pragma unroll
      for (int c = 0; c < 4; ++c) {
        short8 kb = *(const short8*)&kp[c * 32];
        sc[nh] = __builtin_amdgcn_mfma_f32_16x16x32_bf16(aq[c], kb, sc[nh], 0, 0, 0);
      }
    }
    #pragma unroll
    for (int nh = 0; nh < 2; ++nh) {
      int col = k0 + nh * 16 + l16;
      #pragma unroll
      for (int r = 0; r < 4; ++r) {
        int row = q0 + quad * 4 + r;
        float v = sc[nh][r] * scale;
        sc[nh][r] = (col <= row) ? v : -1e30f;
      }
    }
    float alpha[4];
    #pragma unroll
    for (int r = 0; r < 4; ++r) {
      float mx = fmaxf(sc[0][r], sc[1][r]);
      mx = fmaxf(mx, __shfl_xor(mx, 1));
      mx = fmaxf(mx, __shfl_xor(mx, 2));
      mx = fmaxf(mx, __shfl_xor(mx, 4));
      mx = fmaxf(mx, __shfl_xor(mx, 8));
      float mnew = fmaxf(m_run[r], mx);
      alpha[r] = __expf(m_run[r] - mnew);
      m_run[r] = mnew;
      sc[0][r] = __expf(sc[0][r] - mnew);
      sc[1][r] = __expf(sc[1][r] - mnew);
      float sm = sc[0][r] + sc[1][r];
      sm += __shfl_xor(sm, 1);
      sm += __shfl_xor(sm, 2);
      sm += __shfl_xor(sm, 4);
      sm += __shfl_xor(sm, 8);
      l_run[r] = l_run[r] * alpha[r] + sm;
    }
    #pragma unroll
    for (int d = 0; d < 8; ++d) {
      o[d][0] *= alpha[0]; o[d][1] *= alpha[1];
      o[d][2] *= alpha[2]; o[d][3] *= alpha[3];
    }
    __syncthreads();
    #pragma unroll
    for (int nh = 0; nh < 2; ++nh)
      #pragma unroll
      for (int r = 0; r < 4; ++r)
        Ps[quad * 4 + r][nh * 16 + l16] = __float2bfloat16(sc[nh][r]);
    __syncthreads();
    short8 pf = *(const short8*)&Ps[l16][quad * 8];
    #pragma unroll
    for (int d = 0; d < 8; ++d) {
      short8 vb = *(const short8*)&Vb[(size_t)(d * 16 + l16) * SDIM + k0 + quad * 8];
      o[d] = __builtin_amdgcn_mfma_f32_16x16x32_bf16(pf, vb, o[d], 0, 0, 0);
    }
  }

  #pragma unroll
  for (int d = 0; d < 8; ++d) {
    #pragma unroll
    for (int r = 0; r < 4; ++r) {
      int row = q0 + quad * 4 + r;
      size_t tok = (size_t)b * SDIM + row;
      ctx[tok * HID + h * HD + d * 16 + l16] = __float2bfloat16(o[d][r] / l_run[r]);
    }
  }
}

// ---------------- launcher ----------------
extern "C" void kernel_launch(void* const* d_in, const int* in_sizes, int n_in,
                              void* d_out, int out_size, void* d_ws, size_t ws_size,
                              hipStream_t stream) {
  const float* hidden = (const float*)d_in[0];
  const float* ln1g = (const float*)d_in[1];
  const float* ln1b = (const float*)d_in[2];
  const float* ln2g = (const float*)d_in[3];
  const float* ln2b = (const float*)d_in[4];
  const float* Wqkv = (const float*)d_in[5];
  const float* bqkv = (const float*)d_in[6];
  const float* Wo   = (const float*)d_in[7];
  const float* bo   = (const float*)d_in[8];
  const float* Wfc  = (const float*)d_in[9];
  const float* bfc  = (const float*)d_in[10];
  const float* Wproj= (const float*)d_in[11];
  const float* bproj= (const float*)d_in[12];

  // Hand-laid workspace (192 MiB total, aliased):
  char* ws = (char*)d_ws;
  const size_t SZ_WQKV = (size_t)QKVW * HID * 2;      // 25,165,824
  const size_t SZ_WO   = (size_t)HID * HID * 2;       //  8,388,608
  const size_t SZ_WFC  = (size_t)FFD * HID * 2;       // 33,554,432
  const size_t SZ_WPROJ= (size_t)HID * FFD * 2;       // 33,554,432
  const size_t SZ_ACT  = (size_t)NTOK * HID * 2;      // 16,777,216
  const size_t SZ_QKV  = (size_t)NTOK * QKVW * 2;     // 50,331,648
  const size_t SZ_VT   = (size_t)BDIM * HDIM * HD * SDIM * 2; // 16,777,216

  bf16* wqkvT = (bf16*)(ws + 0);                                   // dead after QKV gemm
  bf16* woT   = (bf16*)(ws + SZ_WQKV);                             // dead after Wo gemm
  bf16* wfcT  = (bf16*)(ws + SZ_WQKV + SZ_WO);                     // dead after FC gemm
  bf16* wprojT= (bf16*)(ws + SZ_WQKV + SZ_WO + SZ_WFC);            // live to end
  char* actbase = ws + SZ_WQKV + SZ_WO + SZ_WFC + SZ_WPROJ;
  bf16* xln   = (bf16*)(actbase);                                  // dead after QKV gemm
  bf16* mln   = (bf16*)(actbase + SZ_ACT);                         // dead after FC gemm
  bf16* qkvb  = (bf16*)(actbase + 2 * SZ_ACT);                     // dead after flash
  bf16* vT    = (bf16*)(actbase + 2 * SZ_ACT + SZ_QKV);            // dead after flash
  // aliases:
  bf16* ctx   = xln;                 // written by flash (xln dead)
  bf16* attnb = wqkvT;               // written by Wo gemm (wqkvT dead), 8.4 MB < 25 MB
  bf16* hfc   = qkvb;                // 67.1 MB == SZ_QKV + SZ_VT exactly (both dead)

  dim3 tblk(32, 8);
  transpose_cvt<<<dim3(QKVW / 32, HID / 32), tblk, 0, stream>>>(Wqkv, wqkvT, HID, QKVW);
  transpose_cvt<<<dim3(HID / 32, HID / 32), tblk, 0, stream>>>(Wo, woT, HID, HID);
  transpose_cvt<<<dim3(FFD / 32, HID / 32), tblk, 0, stream>>>(Wfc, wfcT, HID, FFD);
  transpose_cvt<<<dim3(HID / 32, FFD / 32), tblk, 0, stream>>>(Wproj, wprojT, FFD, HID);

  ln_both<<<NTOK, 256, 0, stream>>>(hidden, ln1g, ln1b, ln2g, ln2b, xln, mln);

  // qkv = xln @ WqkvT^T + b : M=4096 N=6144 K=2048 -> bf16
  gemm_bt<3><<<dim3(48, 32), 256, 0, stream>>>(xln, wqkvT, bqkv, nullptr, qkvb,
                                               nullptr, nullptr, NTOK, QKVW, HID);

  rope_vt<<<dim3(32, SDIM / 32), 256, 0, stream>>>(qkvb, vT);

  flash_attn<<<dim3(32, SDIM / 16), 64, 0, stream>>>(qkvb, vT, ctx);

  // attn_out = ctx @ Wo + bo : M=4096 N=2048 K=2048 -> bf16
  gemm_bt<3><<<dim3(16, 32), 256, 0, stream>>>(ctx, woT, bo, nullptr, attnb,
                                               nullptr, nullptr, NTOK, HID, HID);

  // hfc = gelu(mln @ Wfc + bfc) : M=4096 N=8192 K=2048 -> bf16
  gemm_bt<1><<<dim3(64, 32), 256, 0, stream>>>(mln, wfcT, bfc, nullptr, hfc,
                                               nullptr, nullptr, NTOK, FFD, HID);

  // out = hfc @ Wproj + bproj + attnb + hidden : M=4096 N=2048 K=8192 -> f32
  gemm_bt<2><<<dim3(16, 32), 256, 0, stream>>>(hfc, wprojT, bproj, (float*)d_out, nullptr,
                                               attnb, hidden, NTOK, HID, FFD);
}

// Round 3
// 1148.535 us; speedup vs baseline: 1.0157x; 1.0157x over previous
//
#include <hip/hip_runtime.h>
#include <hip/hip_bf16.h>
#include <math.h>

#define BDIM 2
#define SDIM 2048
#define HDIM 16
#define HD 128
#define HID 2048
#define FFD 8192
#define NTOK (BDIM*SDIM)
#define QKVW (3*HID)

typedef __hip_bfloat16 bf16;
typedef __attribute__((ext_vector_type(8))) short short8;
typedef __attribute__((ext_vector_type(4))) short short4_;
typedef __attribute__((ext_vector_type(4))) float floatx4;

__device__ inline short bfbits(float f) {
  bf16 h = __float2bfloat16(f);
  short s;
  __builtin_memcpy(&s, &h, 2);
  return s;
}

// ---------------- weight transpose + f32->bf16 convert ----------------
__global__ __launch_bounds__(256) void transpose_cvt(
    const float* __restrict__ W, bf16* __restrict__ Wt, int K, int N)
{
  __shared__ float tile[32][33];
  int n0 = blockIdx.x * 32, k0 = blockIdx.y * 32;
  int tx = threadIdx.x, ty = threadIdx.y;  // 32 x 8
  #pragma unroll
  for (int r = ty; r < 32; r += 8)
    tile[r][tx] = W[(size_t)(k0 + r) * N + n0 + tx];
  __syncthreads();
  #pragma unroll
  for (int r = ty; r < 32; r += 8)
    Wt[(size_t)(n0 + r) * K + k0 + tx] = __float2bfloat16(tile[tx][r]);
}

// ---------------- fused LayerNorm (both LN1 and LN2) ----------------
__global__ __launch_bounds__(256) void ln_both(
    const float* __restrict__ x,
    const float* __restrict__ g1, const float* __restrict__ b1,
    const float* __restrict__ g2, const float* __restrict__ b2,
    bf16* __restrict__ o1, bf16* __restrict__ o2)
{
  int row = blockIdx.x;
  int tid = threadIdx.x;
  const float4* xr = (const float4*)(x + (size_t)row * HID);
  float4 va = xr[tid], vb = xr[tid + 256];
  float s = va.x + va.y + va.z + va.w + vb.x + vb.y + vb.z + vb.w;
  float q = va.x*va.x + va.y*va.y + va.z*va.z + va.w*va.w
          + vb.x*vb.x + vb.y*vb.y + vb.z*vb.z + vb.w*vb.w;
  #pragma unroll
  for (int off = 1; off < 64; off <<= 1) {
    s += __shfl_xor(s, off);
    q += __shfl_xor(q, off);
  }
  __shared__ float red[8];
  int wave = tid >> 6;
  if ((tid & 63) == 0) { red[wave] = s; red[4 + wave] = q; }
  __syncthreads();
  s = red[0] + red[1] + red[2] + red[3];
  q = red[4] + red[5] + red[6] + red[7];
  float mu = s * (1.0f / HID);
  float var = q * (1.0f / HID) - mu * mu;
  float rs = rsqrtf(var + 1e-5f);

  const float4* g1v = (const float4*)g1; const float4* b1v = (const float4*)b1;
  const float4* g2v = (const float4*)g2; const float4* b2v = (const float4*)b2;
  short4_* o1v = (short4_*)(o1 + (size_t)row * HID);
  short4_* o2v = (short4_*)(o2 + (size_t)row * HID);
  #pragma unroll
  for (int p = 0; p < 2; ++p) {
    int e = tid + p * 256;
    float4 xv = (p == 0) ? va : vb;
    float4 gv = g1v[e], bv = b1v[e];
    short4_ pk;
    pk[0] = bfbits((xv.x - mu) * rs * gv.x + bv.x);
    pk[1] = bfbits((xv.y - mu) * rs * gv.y + bv.y);
    pk[2] = bfbits((xv.z - mu) * rs * gv.z + bv.z);
    pk[3] = bfbits((xv.w - mu) * rs * gv.w + bv.w);
    o1v[e] = pk;
    gv = g2v[e]; bv = b2v[e];
    pk[0] = bfbits((xv.x - mu) * rs * gv.x + bv.x);
    pk[1] = bfbits((xv.y - mu) * rs * gv.y + bv.y);
    pk[2] = bfbits((xv.z - mu) * rs * gv.z + bv.z);
    pk[3] = bfbits((xv.w - mu) * rs * gv.w + bv.w);
    o2v[e] = pk;
  }
}

// ---------------- bf16 GEMM, B^T layout (m97 structure) ----------------
// EPI 1: bf16 out = gelu(acc + bias)
// EPI 2: f32 out = acc + bias + (f32)r1b + r2
// EPI 3: bf16 out = acc + bias
template<int EPI>
__global__ __launch_bounds__(256) void gemm_bt(
    const bf16* __restrict__ A, const bf16* __restrict__ Bt,
    const float* __restrict__ bias,
    float* __restrict__ Cf, bf16* __restrict__ Cb,
    const bf16* __restrict__ r1b, const float* __restrict__ r2,
    int M, int N, int K)
{
  __shared__ bf16 As[128 * 32];
  __shared__ bf16 Bs[128 * 32];
  const int tid = threadIdx.x;
  const int wave = tid >> 6, lane = tid & 63;
  const int quad = lane >> 4, l16 = lane & 15;
  const int n0 = blockIdx.x * 128, m0 = blockIdx.y * 128;
  const int wm = (wave >> 1) * 64, wn = (wave & 1) * 64;
  const int lrow = lane >> 2, lcol = (lane & 3) * 8;

  floatx4 acc[4][4];
  #pragma unroll
  for (int i = 0; i < 4; ++i)
    #pragma unroll
    for (int j = 0; j < 4; ++j) acc[i][j] = (floatx4)0.0f;

  const int KT = K >> 5;
  for (int kt = 0; kt < KT; ++kt) {
    #pragma unroll
    for (int t = 0; t < 2; ++t) {
      int c = wave * 2 + t;
      const bf16* ga = A + (size_t)(m0 + c * 16 + lrow) * K + kt * 32 + lcol;
      const bf16* gb = Bt + (size_t)(n0 + c * 16 + lrow) * K + kt * 32 + lcol;
      __builtin_amdgcn_global_load_lds(
          (const __attribute__((address_space(1))) void*)ga,
          (__attribute__((address_space(3))) void*)&As[c * 512], 16, 0, 0);
      __builtin_amdgcn_global_load_lds(
          (const __attribute__((address_space(1))) void*)gb,
          (__attribute__((address_space(3))) void*)&Bs[c * 512], 16, 0, 0);
    }
    __syncthreads();
    short8 av[4], bv[4];
    #pragma unroll
    for (int i = 0; i < 4; ++i)
      av[i] = *(const short8*)&As[(wm + i * 16 + l16) * 32 + quad * 8];
    #pragma unroll
    for (int j = 0; j < 4; ++j)
      bv[j] = *(const short8*)&Bs[(wn + j * 16 + l16) * 32 + quad * 8];
    #pragma unroll
    for (int i = 0; i < 4; ++i)
      #pragma unroll
      for (int j = 0; j < 4; ++j)
        acc[i][j] = __builtin_amdgcn_mfma_f32_16x16x32_bf16(av[i], bv[j], acc[i][j], 0, 0, 0);
    __syncthreads();
  }

  #pragma unroll
  for (int i = 0; i < 4; ++i) {
    #pragma unroll
    for (int j = 0; j < 4; ++j) {
      int col = n0 + wn + j * 16 + l16;
      float bsv = bias[col];
      #pragma unroll
      for (int r = 0; r < 4; ++r) {
        int row = m0 + wm + i * 16 + quad * 4 + r;
        size_t idx = (size_t)row * N + col;
        float v = acc[i][j][r] + bsv;
        if (EPI == 1) {
          v = 0.5f * v * (1.0f + erff(v * 0.70710678118654752f));
          Cb[idx] = __float2bfloat16(v);
        } else if (EPI == 2) {
          Cf[idx] = v + __bfloat162float(r1b[idx]) + r2[idx];
        } else {
          Cb[idx] = __float2bfloat16(v);
        }
      }
    }
  }
}

// ---------------- RoPE in-place on bf16 qkv + V transpose ----------------
__global__ __launch_bounds__(256) void rope_vt(
    bf16* __restrict__ qkv, bf16* __restrict__ vT)
{
  int bh = blockIdx.x, s0 = blockIdx.y * 32;
  int b = bh >> 4, h = bh & 15;
  int tid = threadIdx.x;
  __shared__ bf16 vs[32][136];

  for (int idx = tid; idx < 512; idx += 256) {
    int sl = idx >> 4, d = idx & 15;
    int s = s0 + sl;
    bf16* base = qkv + (size_t)(b * SDIM + s) * QKVW + h * 384;
    float fr = (float)s * expf(-(float)d * 0.5756462732485114f); // ln(10000)/16
    float c = cosf(fr), sn = sinf(fr);
    float q1 = __bfloat162float(base[d]);
    float q2 = __bfloat162float(base[d + 16]);
    float k1 = __bfloat162float(base[128 + d]);
    float k2 = __bfloat162float(base[128 + d + 16]);
    base[d]        = __float2bfloat16(q1 * c - q2 * sn);
    base[d + 16]   = __float2bfloat16(q2 * c + q1 * sn);
    base[128 + d]      = __float2bfloat16(k1 * c - k2 * sn);
    base[128 + d + 16] = __float2bfloat16(k2 * c + k1 * sn);
  }

  for (int idx = tid; idx < 32 * 128; idx += 256) {
    int sl = idx >> 7, d = idx & 127;
    vs[sl][d] = qkv[(size_t)(b * SDIM + s0 + sl) * QKVW + h * 384 + 256 + d];
  }
  __syncthreads();
  for (int idx = tid; idx < 32 * 128; idx += 256) {
    int d = idx >> 5, sl = idx & 31;
    vT[((size_t)bh * HD + d) * SDIM + s0 + sl] = vs[sl][d];
  }
}

// ---------------- flash attention v2 ----------------
// 256-thread blocks; wave w owns q-rows [qb*64 + w*16, +16) independently.
// NO barriers: LDS ops within a wave are ordered by HW; Ps is wave-private.
// Heaviest causal blocks dispatch first (reversed blockIdx.y).
__global__ __launch_bounds__(256) void flash_attn(
    const bf16* __restrict__ qkv, const bf16* __restrict__ vT,
    bf16* __restrict__ ctx)
{
  int bh = blockIdx.x;
  int qb = gridDim.y - 1 - blockIdx.y;   // heavy blocks first
  int b = bh >> 4, h = bh & 15;
  int tid = threadIdx.x;
  int wave = tid >> 6, lane = tid & 63;
  int quad = lane >> 4, l16 = lane & 15;
  int q0 = qb * 64 + wave * 16;
  const bf16* Qb = qkv + (size_t)b * SDIM * QKVW + h * 384;        // +row*6144
  const bf16* Kb = Qb + 128;
  const bf16* Vb = vT + (size_t)bh * HD * SDIM;
  __shared__ bf16 Ps[4][16][32];

  short8 aq[4];
  #pragma unroll
  for (int c = 0; c < 4; ++c)
    aq[c] = *(const short8*)&Qb[(size_t)(q0 + l16) * QKVW + c * 32 + quad * 8];

  floatx4 o[8];
  #pragma unroll
  for (int d = 0; d < 8; ++d) o[d] = (floatx4)0.0f;
  float m_run[4] = {-INFINITY, -INFINITY, -INFINITY, -INFINITY};
  float l_run[4] = {0.0f, 0.0f, 0.0f, 0.0f};
  const float scale = 0.08838834764831845f;  // 1/sqrt(128)

  int tmax = (q0 + 15) >> 5;
  for (int t = 0; t <= tmax; ++t) {
    int k0 = t * 32;
    floatx4 sc[2];
    sc[0] = (floatx4)0.0f; sc[1] = (floatx4)0.0f;
    #pragma unroll
    for (int nh = 0; nh < 2; ++nh) {
      const bf16* kp = &Kb[(size_t)(k0 + nh * 16 + l16) * QKVW + quad * 8];
      #pragma unroll
      for (int c = 0; c < 4; ++c) {
        short8 kb = *(const short8*)&kp[c * 32];
        sc[nh] = __builtin_amdgcn_mfma_f32_16x16x32_bf16(aq[c], kb, sc[nh], 0, 0, 0);
      }
    }
    #pragma unroll
    for (int nh = 0; nh < 2; ++nh) {
      int col = k0 + nh * 16 + l16;
      #pragma unroll
      for (int r = 0; r < 4; ++r) {
        int row = q0 + quad * 4 + r;
        float v = sc[nh][r] * scale;
        sc[nh][r] = (col <= row) ? v : -1e30f;
      }
    }
    float alpha[4];
    #pragma unroll
    for (int r = 0; r < 4; ++r) {
      float mx = fmaxf(sc[0][r], sc[1][r]);
      mx = fmaxf(mx, __shfl_xor(mx, 1));
      mx = fmaxf(mx, __shfl_xor(mx, 2));
      mx = fmaxf(mx, __shfl_xor(mx, 4));
      mx = fmaxf(mx, __shfl_xor(mx, 8));
      float mnew = fmaxf(m_run[r], mx);
      alpha[r] = __expf(m_run[r] - mnew);
      m_run[r] = mnew;
      sc[0][r] = __expf(sc[0][r] - mnew);
      sc[1][r] = __expf(sc[1][r] - mnew);
      float sm = sc[0][r] + sc[1][r];
      sm += __shfl_xor(sm, 1);
      sm += __shfl_xor(sm, 2);
      sm += __shfl_xor(sm, 4);
      sm += __shfl_xor(sm, 8);
      l_run[r] = l_run[r] * alpha[r] + sm;
    }
    #pragma unroll
    for (int d = 0; d < 8; ++d) {
      o[d][0] *= alpha[0]; o[d][1] *= alpha[1];
      o[d][2] *= alpha[2]; o[d][3] *= alpha[3];
    }
    // P: C-layout -> A-layout via wave-private LDS slab (no barrier needed:
    // same-wave DS ops are ordered by hardware, waitcnt covers the read)
    #pragma unroll
    for (int nh = 0; nh < 2; ++nh)
      #pragma unroll
      for (int r = 0; r < 4; ++r)
        Ps[wave][quad * 4 + r][nh * 16 + l16] = __float2bfloat16(sc[nh][r]);
    short8 pf = *(const short8*)&Ps[wave][l16][quad * 8];
    #pragma unroll
    for (int d = 0; d < 8; ++d) {
      short8 vb = *(const short8*)&Vb[(size_t)(d * 16 + l16) * SDIM + k0 + quad * 8];
      o[d] = __builtin_amdgcn_mfma_f32_16x16x32_bf16(pf, vb, o[d], 0, 0, 0);
    }
  }

  #pragma unroll
  for (int d = 0; d < 8; ++d) {
    #pragma unroll
    for (int r = 0; r < 4; ++r) {
      int row = q0 + quad * 4 + r;
      size_t tok = (size_t)b * SDIM + row;
      ctx[tok * HID + h * HD + d * 16 + l16] = __float2bfloat16(o[d][r] / l_run[r]);
    }
  }
}

// ---------------- launcher ----------------
extern "C" void kernel_launch(void* const* d_in, const int* in_sizes, int n_in,
                              void* d_out, int out_size, void* d_ws, size_t ws_size,
                              hipStream_t stream) {
  const float* hidden = (const float*)d_in[0];
  const float* ln1g = (const float*)d_in[1];
  const float* ln1b = (const float*)d_in[2];
  const float* ln2g = (const float*)d_in[3];
  const float* ln2b = (const float*)d_in[4];
  const float* Wqkv = (const float*)d_in[5];
  const float* bqkv = (const float*)d_in[6];
  const float* Wo   = (const float*)d_in[7];
  const float* bo   = (const float*)d_in[8];
  const float* Wfc  = (const float*)d_in[9];
  const float* bfc  = (const float*)d_in[10];
  const float* Wproj= (const float*)d_in[11];
  const float* bproj= (const float*)d_in[12];

  char* ws = (char*)d_ws;
  const size_t SZ_WQKV = (size_t)QKVW * HID * 2;
  const size_t SZ_WO   = (size_t)HID * HID * 2;
  const size_t SZ_WFC  = (size_t)FFD * HID * 2;
  const size_t SZ_WPROJ= (size_t)HID * FFD * 2;
  const size_t SZ_ACT  = (size_t)NTOK * HID * 2;
  const size_t SZ_QKV  = (size_t)NTOK * QKVW * 2;

  bf16* wqkvT = (bf16*)(ws + 0);
  bf16* woT   = (bf16*)(ws + SZ_WQKV);
  bf16* wfcT  = (bf16*)(ws + SZ_WQKV + SZ_WO);
  bf16* wprojT= (bf16*)(ws + SZ_WQKV + SZ_WO + SZ_WFC);
  char* actbase = ws + SZ_WQKV + SZ_WO + SZ_WFC + SZ_WPROJ;
  bf16* xln   = (bf16*)(actbase);
  bf16* mln   = (bf16*)(actbase + SZ_ACT);
  bf16* qkvb  = (bf16*)(actbase + 2 * SZ_ACT);
  bf16* vT    = (bf16*)(actbase + 2 * SZ_ACT + SZ_QKV);
  bf16* ctx   = xln;
  bf16* attnb = wqkvT;
  bf16* hfc   = qkvb;

  dim3 tblk(32, 8);
  transpose_cvt<<<dim3(QKVW / 32, HID / 32), tblk, 0, stream>>>(Wqkv, wqkvT, HID, QKVW);
  transpose_cvt<<<dim3(HID / 32, HID / 32), tblk, 0, stream>>>(Wo, woT, HID, HID);
  transpose_cvt<<<dim3(FFD / 32, HID / 32), tblk, 0, stream>>>(Wfc, wfcT, HID, FFD);
  transpose_cvt<<<dim3(HID / 32, FFD / 32), tblk, 0, stream>>>(Wproj, wprojT, FFD, HID);

  ln_both<<<NTOK, 256, 0, stream>>>(hidden, ln1g, ln1b, ln2g, ln2b, xln, mln);

  gemm_bt<3><<<dim3(48, 32), 256, 0, stream>>>(xln, wqkvT, bqkv, nullptr, qkvb,
                                               nullptr, nullptr, NTOK, QKVW, HID);

  rope_vt<<<dim3(32, SDIM / 32), 256, 0, stream>>>(qkvb, vT);

  flash_attn<<<dim3(32, SDIM / 64), 256, 0, stream>>>(qkvb, vT, ctx);

  gemm_bt<3><<<dim3(16, 32), 256, 0, stream>>>(ctx, woT, bo, nullptr, attnb,
                                               nullptr, nullptr, NTOK, HID, HID);

  gemm_bt<1><<<dim3(64, 32), 256, 0, stream>>>(mln, wfcT, bfc, nullptr, hfc,
                                               nullptr, nullptr, NTOK, FFD, HID);

  gemm_bt<2><<<dim3(16, 32), 256, 0, stream>>>(hfc, wprojT, bproj, (float*)d_out, nullptr,
                                               attnb, hidden, NTOK, HID, FFD);
}

// Round 4
// 1100.346 us; speedup vs baseline: 1.0602x; 1.0438x over previous
//
#include <hip/hip_runtime.h>
#include <hip/hip_bf16.h>
#include <math.h>

#define BDIM 2
#define SDIM 2048
#define HDIM 16
#define HD 128
#define HID 2048
#define FFD 8192
#define NTOK (BDIM*SDIM)
#define QKVW (3*HID)

typedef __hip_bfloat16 bf16;
typedef __attribute__((ext_vector_type(8))) short short8;
typedef __attribute__((ext_vector_type(4))) short short4_;
typedef __attribute__((ext_vector_type(4))) float floatx4;

__device__ inline short bfbits(float f) {
  bf16 h = __float2bfloat16(f);
  short s;
  __builtin_memcpy(&s, &h, 2);
  return s;
}

// ---------------- weight transpose + f32->bf16 convert ----------------
__global__ __launch_bounds__(256) void transpose_cvt(
    const float* __restrict__ W, bf16* __restrict__ Wt, int K, int N)
{
  __shared__ float tile[32][33];
  int n0 = blockIdx.x * 32, k0 = blockIdx.y * 32;
  int tx = threadIdx.x, ty = threadIdx.y;  // 32 x 8
  #pragma unroll
  for (int r = ty; r < 32; r += 8)
    tile[r][tx] = W[(size_t)(k0 + r) * N + n0 + tx];
  __syncthreads();
  #pragma unroll
  for (int r = ty; r < 32; r += 8)
    Wt[(size_t)(n0 + r) * K + k0 + tx] = __float2bfloat16(tile[tx][r]);
}

// ---------------- fused LayerNorm (both LN1 and LN2) ----------------
__global__ __launch_bounds__(256) void ln_both(
    const float* __restrict__ x,
    const float* __restrict__ g1, const float* __restrict__ b1,
    const float* __restrict__ g2, const float* __restrict__ b2,
    bf16* __restrict__ o1, bf16* __restrict__ o2)
{
  int row = blockIdx.x;
  int tid = threadIdx.x;
  const float4* xr = (const float4*)(x + (size_t)row * HID);
  float4 va = xr[tid], vb = xr[tid + 256];
  float s = va.x + va.y + va.z + va.w + vb.x + vb.y + vb.z + vb.w;
  float q = va.x*va.x + va.y*va.y + va.z*va.z + va.w*va.w
          + vb.x*vb.x + vb.y*vb.y + vb.z*vb.z + vb.w*vb.w;
  #pragma unroll
  for (int off = 1; off < 64; off <<= 1) {
    s += __shfl_xor(s, off);
    q += __shfl_xor(q, off);
  }
  __shared__ float red[8];
  int wave = tid >> 6;
  if ((tid & 63) == 0) { red[wave] = s; red[4 + wave] = q; }
  __syncthreads();
  s = red[0] + red[1] + red[2] + red[3];
  q = red[4] + red[5] + red[6] + red[7];
  float mu = s * (1.0f / HID);
  float var = q * (1.0f / HID) - mu * mu;
  float rs = rsqrtf(var + 1e-5f);

  const float4* g1v = (const float4*)g1; const float4* b1v = (const float4*)b1;
  const float4* g2v = (const float4*)g2; const float4* b2v = (const float4*)b2;
  short4_* o1v = (short4_*)(o1 + (size_t)row * HID);
  short4_* o2v = (short4_*)(o2 + (size_t)row * HID);
  #pragma unroll
  for (int p = 0; p < 2; ++p) {
    int e = tid + p * 256;
    float4 xv = (p == 0) ? va : vb;
    float4 gv = g1v[e], bv = b1v[e];
    short4_ pk;
    pk[0] = bfbits((xv.x - mu) * rs * gv.x + bv.x);
    pk[1] = bfbits((xv.y - mu) * rs * gv.y + bv.y);
    pk[2] = bfbits((xv.z - mu) * rs * gv.z + bv.z);
    pk[3] = bfbits((xv.w - mu) * rs * gv.w + bv.w);
    o1v[e] = pk;
    gv = g2v[e]; bv = b2v[e];
    pk[0] = bfbits((xv.x - mu) * rs * gv.x + bv.x);
    pk[1] = bfbits((xv.y - mu) * rs * gv.y + bv.y);
    pk[2] = bfbits((xv.z - mu) * rs * gv.z + bv.z);
    pk[3] = bfbits((xv.w - mu) * rs * gv.w + bv.w);
    o2v[e] = pk;
  }
}

// ---------------- bf16 GEMM, B^T layout (m97 structure) ----------------
// EPI 1: bf16 out = gelu(acc + bias)
// EPI 2: f32 out = acc + bias + (f32)r1b + r2
// EPI 3: bf16 out = acc + bias
template<int EPI>
__global__ __launch_bounds__(256) void gemm_bt(
    const bf16* __restrict__ A, const bf16* __restrict__ Bt,
    const float* __restrict__ bias,
    float* __restrict__ Cf, bf16* __restrict__ Cb,
    const bf16* __restrict__ r1b, const float* __restrict__ r2,
    int M, int N, int K)
{
  __shared__ bf16 As[128 * 32];
  __shared__ bf16 Bs[128 * 32];
  const int tid = threadIdx.x;
  const int wave = tid >> 6, lane = tid & 63;
  const int quad = lane >> 4, l16 = lane & 15;
  const int n0 = blockIdx.x * 128, m0 = blockIdx.y * 128;
  const int wm = (wave >> 1) * 64, wn = (wave & 1) * 64;
  const int lrow = lane >> 2, lcol = (lane & 3) * 8;

  floatx4 acc[4][4];
  #pragma unroll
  for (int i = 0; i < 4; ++i)
    #pragma unroll
    for (int j = 0; j < 4; ++j) acc[i][j] = (floatx4)0.0f;

  const int KT = K >> 5;
  for (int kt = 0; kt < KT; ++kt) {
    #pragma unroll
    for (int t = 0; t < 2; ++t) {
      int c = wave * 2 + t;
      const bf16* ga = A + (size_t)(m0 + c * 16 + lrow) * K + kt * 32 + lcol;
      const bf16* gb = Bt + (size_t)(n0 + c * 16 + lrow) * K + kt * 32 + lcol;
      __builtin_amdgcn_global_load_lds(
          (const __attribute__((address_space(1))) void*)ga,
          (__attribute__((address_space(3))) void*)&As[c * 512], 16, 0, 0);
      __builtin_amdgcn_global_load_lds(
          (const __attribute__((address_space(1))) void*)gb,
          (__attribute__((address_space(3))) void*)&Bs[c * 512], 16, 0, 0);
    }
    __syncthreads();
    short8 av[4], bv[4];
    #pragma unroll
    for (int i = 0; i < 4; ++i)
      av[i] = *(const short8*)&As[(wm + i * 16 + l16) * 32 + quad * 8];
    #pragma unroll
    for (int j = 0; j < 4; ++j)
      bv[j] = *(const short8*)&Bs[(wn + j * 16 + l16) * 32 + quad * 8];
    #pragma unroll
    for (int i = 0; i < 4; ++i)
      #pragma unroll
      for (int j = 0; j < 4; ++j)
        acc[i][j] = __builtin_amdgcn_mfma_f32_16x16x32_bf16(av[i], bv[j], acc[i][j], 0, 0, 0);
    __syncthreads();
  }

  #pragma unroll
  for (int i = 0; i < 4; ++i) {
    #pragma unroll
    for (int j = 0; j < 4; ++j) {
      int col = n0 + wn + j * 16 + l16;
      float bsv = bias[col];
      #pragma unroll
      for (int r = 0; r < 4; ++r) {
        int row = m0 + wm + i * 16 + quad * 4 + r;
        size_t idx = (size_t)row * N + col;
        float v = acc[i][j][r] + bsv;
        if (EPI == 1) {
          v = 0.5f * v * (1.0f + erff(v * 0.70710678118654752f));
          Cb[idx] = __float2bfloat16(v);
        } else if (EPI == 2) {
          Cf[idx] = v + __bfloat162float(r1b[idx]) + r2[idx];
        } else {
          Cb[idx] = __float2bfloat16(v);
        }
      }
    }
  }
}

// ---------------- RoPE in-place + Q pre-scale + V transpose ----------------
// Q is pre-scaled by (1/sqrt(128))*log2(e) so flash can use exp2 directly.
__global__ __launch_bounds__(256) void rope_vt(
    bf16* __restrict__ qkv, bf16* __restrict__ vT)
{
  int bh = blockIdx.x, s0 = blockIdx.y * 32;
  int b = bh >> 4, h = bh & 15;
  int tid = threadIdx.x;
  __shared__ bf16 vs[32][136];
  const float qsc = 0.12751740f;  // (1/sqrt(128)) * log2(e)

  // rot pairs: 32 tokens x 16 pairs (q scaled, k not)
  for (int idx = tid; idx < 512; idx += 256) {
    int sl = idx >> 4, d = idx & 15;
    int s = s0 + sl;
    bf16* base = qkv + (size_t)(b * SDIM + s) * QKVW + h * 384;
    float fr = (float)s * expf(-(float)d * 0.5756462732485114f); // ln(10000)/16
    float c = cosf(fr), sn = sinf(fr);
    float q1 = __bfloat162float(base[d]);
    float q2 = __bfloat162float(base[d + 16]);
    float k1 = __bfloat162float(base[128 + d]);
    float k2 = __bfloat162float(base[128 + d + 16]);
    base[d]        = __float2bfloat16(qsc * (q1 * c - q2 * sn));
    base[d + 16]   = __float2bfloat16(qsc * (q2 * c + q1 * sn));
    base[128 + d]      = __float2bfloat16(k1 * c - k2 * sn);
    base[128 + d + 16] = __float2bfloat16(k2 * c + k1 * sn);
  }
  // scale remaining q dims [32,128): 32 tokens x 96 dims
  for (int idx = tid; idx < 32 * 96; idx += 256) {
    int sl = idx / 96, d = 32 + idx % 96;
    bf16* base = qkv + (size_t)(b * SDIM + s0 + sl) * QKVW + h * 384;
    base[d] = __float2bfloat16(qsc * __bfloat162float(base[d]));
  }

  for (int idx = tid; idx < 32 * 128; idx += 256) {
    int sl = idx >> 7, d = idx & 127;
    vs[sl][d] = qkv[(size_t)(b * SDIM + s0 + sl) * QKVW + h * 384 + 256 + d];
  }
  __syncthreads();
  for (int idx = tid; idx < 32 * 128; idx += 256) {
    int d = idx >> 5, sl = idx & 31;
    vT[((size_t)bh * HD + d) * SDIM + s0 + sl] = vs[sl][d];
  }
}

// ---------------- flash attention v3 ----------------
// Wave w of block (bh, y) handles pair p = y*4+w: q-tiles at qa=16p (light)
// and qb=S-16(p+1) (heavy). Combined keys = S+16 (constant -> perfect
// balance); K/V loads shared by both tiles. Register double-buffered K
// prefetch; V issued at iteration top. exp2-domain softmax (Q pre-scaled).
#define LOAD_K(KB, K0) { \
  int krow_ = (K0); \
  _Pragma("unroll") for (int nh_ = 0; nh_ < 2; ++nh_) \
    _Pragma("unroll") for (int c_ = 0; c_ < 4; ++c_) \
      KB[nh_*4+c_] = *(const short8*)&Kb[(size_t)(krow_ + nh_*16 + l16) * QKVW + c_*32 + quad*8]; }

#define SOFTMAX(S0, S1, MR, LR, OO, ROWQ, DOMASK, K0, SLOT) { \
  if (DOMASK) { \
    _Pragma("unroll") for (int r_ = 0; r_ < 4; ++r_) { \
      int row_ = (ROWQ) + quad*4 + r_; \
      S0[r_] = ((K0) + l16 <= row_) ? S0[r_] : -1e30f; \
      S1[r_] = ((K0) + 16 + l16 <= row_) ? S1[r_] : -1e30f; } } \
  _Pragma("unroll") for (int r_ = 0; r_ < 4; ++r_) { \
    float mx_ = fmaxf(S0[r_], S1[r_]); \
    mx_ = fmaxf(mx_, __shfl_xor(mx_, 1)); \
    mx_ = fmaxf(mx_, __shfl_xor(mx_, 2)); \
    mx_ = fmaxf(mx_, __shfl_xor(mx_, 4)); \
    mx_ = fmaxf(mx_, __shfl_xor(mx_, 8)); \
    float mnew_ = fmaxf(MR[r_], mx_); \
    float alpha_ = __builtin_amdgcn_exp2f(MR[r_] - mnew_); \
    MR[r_] = mnew_; \
    S0[r_] = __builtin_amdgcn_exp2f(S0[r_] - mnew_); \
    S1[r_] = __builtin_amdgcn_exp2f(S1[r_] - mnew_); \
    float sm_ = S0[r_] + S1[r_]; \
    sm_ += __shfl_xor(sm_, 1); sm_ += __shfl_xor(sm_, 2); \
    sm_ += __shfl_xor(sm_, 4); sm_ += __shfl_xor(sm_, 8); \
    LR[r_] = LR[r_] * alpha_ + sm_; \
    _Pragma("unroll") for (int d_ = 0; d_ < 8; ++d_) OO[d_][r_] *= alpha_; \
    Ps[wave][SLOT][quad*4 + r_][l16]      = __float2bfloat16(S0[r_]); \
    Ps[wave][SLOT][quad*4 + r_][16 + l16] = __float2bfloat16(S1[r_]); } }

#define FLASH_ITER(IT, KC, KN) { \
  const int k0_ = (IT) * 32; \
  const int k0n_ = ((IT) + 1 < nk) ? k0_ + 32 : 0; \
  LOAD_K(KN, k0n_); \
  short8 vbuf_[8]; \
  _Pragma("unroll") for (int d_ = 0; d_ < 8; ++d_) \
    vbuf_[d_] = *(const short8*)&Vb[(size_t)(d_*16 + l16) * SDIM + k0_ + quad*8]; \
  floatx4 scB_[2]; scB_[0] = (floatx4)0.0f; scB_[1] = (floatx4)0.0f; \
  _Pragma("unroll") for (int c_ = 0; c_ < 4; ++c_) { \
    scB_[0] = __builtin_amdgcn_mfma_f32_16x16x32_bf16(aqB[c_], KC[c_],   scB_[0], 0,0,0); \
    scB_[1] = __builtin_amdgcn_mfma_f32_16x16x32_bf16(aqB[c_], KC[4+c_], scB_[1], 0,0,0); } \
  const bool actA_ = (k0_ <= qa + 15); \
  floatx4 scA_[2]; scA_[0] = (floatx4)0.0f; scA_[1] = (floatx4)0.0f; \
  if (actA_) { \
    _Pragma("unroll") for (int c_ = 0; c_ < 4; ++c_) { \
      scA_[0] = __builtin_amdgcn_mfma_f32_16x16x32_bf16(aqA[c_], KC[c_],   scA_[0], 0,0,0); \
      scA_[1] = __builtin_amdgcn_mfma_f32_16x16x32_bf16(aqA[c_], KC[4+c_], scA_[1], 0,0,0); } } \
  SOFTMAX(scB_[0], scB_[1], mB, lB, oB, qb, (k0_ + 32 >= kmax), k0_, 0); \
  if (actA_) { \
    SOFTMAX(scA_[0], scA_[1], mA, lA, oA, qa, (k0_ + 32 > qa + 15), k0_, 1); \
    short8 pfB_ = *(const short8*)&Ps[wave][0][l16][quad*8]; \
    short8 pfA_ = *(const short8*)&Ps[wave][1][l16][quad*8]; \
    _Pragma("unroll") for (int d_ = 0; d_ < 8; ++d_) { \
      oB[d_] = __builtin_amdgcn_mfma_f32_16x16x32_bf16(pfB_, vbuf_[d_], oB[d_], 0,0,0); \
      oA[d_] = __builtin_amdgcn_mfma_f32_16x16x32_bf16(pfA_, vbuf_[d_], oA[d_], 0,0,0); } \
  } else { \
    short8 pfB_ = *(const short8*)&Ps[wave][0][l16][quad*8]; \
    _Pragma("unroll") for (int d_ = 0; d_ < 8; ++d_) \
      oB[d_] = __builtin_amdgcn_mfma_f32_16x16x32_bf16(pfB_, vbuf_[d_], oB[d_], 0,0,0); } }

__global__ __launch_bounds__(256) void flash_attn(
    const bf16* __restrict__ qkv, const bf16* __restrict__ vT,
    bf16* __restrict__ ctx)
{
  int bh = blockIdx.x;
  int b = bh >> 4, h = bh & 15;
  int tid = threadIdx.x;
  int wave = tid >> 6, lane = tid & 63;
  int quad = lane >> 4, l16 = lane & 15;
  int p = blockIdx.y * 4 + wave;       // 0..63
  int qa = 16 * p;
  int qb = SDIM - 16 * (p + 1);
  int kmax = qb + 16;
  int nk = (kmax + 31) >> 5;
  const bf16* Qb = qkv + (size_t)b * SDIM * QKVW + h * 384;
  const bf16* Kb = Qb + 128;
  const bf16* Vb = vT + (size_t)bh * HD * SDIM;
  __shared__ bf16 Ps[4][2][16][32];

  short8 aqA[4], aqB[4];
  #pragma unroll
  for (int c = 0; c < 4; ++c) {
    aqA[c] = *(const short8*)&Qb[(size_t)(qa + l16) * QKVW + c * 32 + quad * 8];
    aqB[c] = *(const short8*)&Qb[(size_t)(qb + l16) * QKVW + c * 32 + quad * 8];
  }

  floatx4 oA[8], oB[8];
  #pragma unroll
  for (int d = 0; d < 8; ++d) { oA[d] = (floatx4)0.0f; oB[d] = (floatx4)0.0f; }
  float mA[4] = {-INFINITY, -INFINITY, -INFINITY, -INFINITY};
  float mB[4] = {-INFINITY, -INFINITY, -INFINITY, -INFINITY};
  float lA[4] = {0.0f, 0.0f, 0.0f, 0.0f};
  float lB[4] = {0.0f, 0.0f, 0.0f, 0.0f};

  short8 kb0[8], kb1[8];
  LOAD_K(kb0, 0);
  for (int it = 0; it < nk; it += 2) {
    FLASH_ITER(it, kb0, kb1);
    if (it + 1 < nk) { FLASH_ITER(it + 1, kb1, kb0); }
  }

  float rlA[4], rlB[4];
  #pragma unroll
  for (int r = 0; r < 4; ++r) { rlA[r] = 1.0f / lA[r]; rlB[r] = 1.0f / lB[r]; }
  #pragma unroll
  for (int d = 0; d < 8; ++d) {
    #pragma unroll
    for (int r = 0; r < 4; ++r) {
      int rowA = qa + quad * 4 + r;
      int rowB = qb + quad * 4 + r;
      ctx[((size_t)b * SDIM + rowA) * HID + h * HD + d * 16 + l16] =
          __float2bfloat16(oA[d][r] * rlA[r]);
      ctx[((size_t)b * SDIM + rowB) * HID + h * HD + d * 16 + l16] =
          __float2bfloat16(oB[d][r] * rlB[r]);
    }
  }
}

// ---------------- launcher ----------------
extern "C" void kernel_launch(void* const* d_in, const int* in_sizes, int n_in,
                              void* d_out, int out_size, void* d_ws, size_t ws_size,
                              hipStream_t stream) {
  const float* hidden = (const float*)d_in[0];
  const float* ln1g = (const float*)d_in[1];
  const float* ln1b = (const float*)d_in[2];
  const float* ln2g = (const float*)d_in[3];
  const float* ln2b = (const float*)d_in[4];
  const float* Wqkv = (const float*)d_in[5];
  const float* bqkv = (const float*)d_in[6];
  const float* Wo   = (const float*)d_in[7];
  const float* bo   = (const float*)d_in[8];
  const float* Wfc  = (const float*)d_in[9];
  const float* bfc  = (const float*)d_in[10];
  const float* Wproj= (const float*)d_in[11];
  const float* bproj= (const float*)d_in[12];

  char* ws = (char*)d_ws;
  const size_t SZ_WQKV = (size_t)QKVW * HID * 2;
  const size_t SZ_WO   = (size_t)HID * HID * 2;
  const size_t SZ_WFC  = (size_t)FFD * HID * 2;
  const size_t SZ_WPROJ= (size_t)HID * FFD * 2;
  const size_t SZ_ACT  = (size_t)NTOK * HID * 2;
  const size_t SZ_QKV  = (size_t)NTOK * QKVW * 2;

  bf16* wqkvT = (bf16*)(ws + 0);
  bf16* woT   = (bf16*)(ws + SZ_WQKV);
  bf16* wfcT  = (bf16*)(ws + SZ_WQKV + SZ_WO);
  bf16* wprojT= (bf16*)(ws + SZ_WQKV + SZ_WO + SZ_WFC);
  char* actbase = ws + SZ_WQKV + SZ_WO + SZ_WFC + SZ_WPROJ;
  bf16* xln   = (bf16*)(actbase);
  bf16* mln   = (bf16*)(actbase + SZ_ACT);
  bf16* qkvb  = (bf16*)(actbase + 2 * SZ_ACT);
  bf16* vT    = (bf16*)(actbase + 2 * SZ_ACT + SZ_QKV);
  bf16* ctx   = xln;
  bf16* attnb = wqkvT;
  bf16* hfc   = qkvb;

  dim3 tblk(32, 8);
  transpose_cvt<<<dim3(QKVW / 32, HID / 32), tblk, 0, stream>>>(Wqkv, wqkvT, HID, QKVW);
  transpose_cvt<<<dim3(HID / 32, HID / 32), tblk, 0, stream>>>(Wo, woT, HID, HID);
  transpose_cvt<<<dim3(FFD / 32, HID / 32), tblk, 0, stream>>>(Wfc, wfcT, HID, FFD);
  transpose_cvt<<<dim3(HID / 32, FFD / 32), tblk, 0, stream>>>(Wproj, wprojT, FFD, HID);

  ln_both<<<NTOK, 256, 0, stream>>>(hidden, ln1g, ln1b, ln2g, ln2b, xln, mln);

  gemm_bt<3><<<dim3(48, 32), 256, 0, stream>>>(xln, wqkvT, bqkv, nullptr, qkvb,
                                               nullptr, nullptr, NTOK, QKVW, HID);

  rope_vt<<<dim3(32, SDIM / 32), 256, 0, stream>>>(qkvb, vT);

  flash_attn<<<dim3(32, SDIM / 128), 256, 0, stream>>>(qkvb, vT, ctx);

  gemm_bt<3><<<dim3(16, 32), 256, 0, stream>>>(ctx, woT, bo, nullptr, attnb,
                                               nullptr, nullptr, NTOK, HID, HID);

  gemm_bt<1><<<dim3(64, 32), 256, 0, stream>>>(mln, wfcT, bfc, nullptr, hfc,
                                               nullptr, nullptr, NTOK, FFD, HID);

  gemm_bt<2><<<dim3(16, 32), 256, 0, stream>>>(hfc, wprojT, bproj, (float*)d_out, nullptr,
                                               attnb, hidden, NTOK, HID, FFD);
}